// Round 4
// baseline (261.311 us; speedup 1.0000x reference)
//
#include <hip/hip_runtime.h>
#include <hip/hip_bf16.h>
#include <math.h>

// Problem constants (fixed by setup_inputs)
#define BATCH 4
#define NHEAD 8
#define HD 24          // head dim
#define CH 192         // total channels
#define HW 16384       // h*w
#define SPL 128        // kA hw-splits (128 hw each)
#define SPHW 128
#define SROW 640       // Sp row: [0,576) gram, [576,600) sqq, [600,624) sqk, pad to 640

// ws layout (floats):
//   Sp: [32 bh][128 sp][640]   off 0        (10.49 MB)
//   Mo: ushort[4][192][192]    off OFF_MO   (288 KB)
#define OFF_MO (32 * SPL * SROW)

typedef __attribute__((ext_vector_type(8)))  short bf16x8;
typedef __attribute__((ext_vector_type(16))) float f32x16;

__device__ __forceinline__ float dot4(const float4& a, const float4& b) {
    return fmaf(a.x, b.x, fmaf(a.y, b.y, fmaf(a.z, b.z, a.w * b.w)));
}

__device__ __forceinline__ unsigned short bf16rne(float x) {
    union { float f; unsigned u; } v; v.f = x;
    unsigned u = v.u;
    return (unsigned short)((u + 0x7FFFu + ((u >> 16) & 1u)) >> 16);
}

// pack 8 fp32 -> bf16x8 (RNE, packed-cvt HW path)
__device__ __forceinline__ bf16x8 pack8(const float4& a, const float4& b) {
    union { __hip_bfloat162 h; unsigned u; } c0, c1, c2, c3;
    c0.h = __float22bfloat162_rn(float2{a.x, a.y});
    c1.h = __float22bfloat162_rn(float2{a.z, a.w});
    c2.h = __float22bfloat162_rn(float2{b.x, b.y});
    c3.h = __float22bfloat162_rn(float2{b.z, b.w});
    union { unsigned u[4]; bf16x8 v; } r;
    r.u[0] = c0.u; r.u[1] = c1.u; r.u[2] = c2.u; r.u[3] = c3.u;
    return r.v;
}

// ---------------------------------------------------------------------------
// Kernel A: streaming Gram via mfma_32x32x16 (24x24 fits one 32x32 tile).
// Per wave: one 128-hw split; 8 steps of (4 float4 loads, 2 packs, 1 MFMA).
// No LDS, no barriers. Sumsq folded in registers. Wave writes its 640-float
// Sp row contiguously (no write amplification).
// grid (32 bh, 64), block 128 (2 waves; wave w -> split blockIdx.y*2+w).
// ---------------------------------------------------------------------------
__global__ __launch_bounds__(128, 4) void kA(const float* __restrict__ q,
                                             const float* __restrict__ k,
                                             float* __restrict__ ws) {
    const int bh   = blockIdx.x;
    const int t    = threadIdx.x;
    const int wave = t >> 6;
    const int lane = t & 63;
    const int sp   = blockIdx.y * 2 + wave;   // 0..127
    const int row  = lane & 31;               // channel within head (A/B m,n)
    const int hi   = lane >> 5;               // k-subgroup (8 hw each)
    const bool rv  = row < HD;

    const float* qb = q + (size_t)bh * HD * HW + (size_t)row * HW;
    const float* kb = k + (size_t)bh * HD * HW + (size_t)row * HW;

    f32x16 acc = {};
    float sq = 0.f, sk = 0.f;
    const int base = sp * SPHW + hi * 8;
    const float4 z4 = make_float4(0.f, 0.f, 0.f, 0.f);

    #pragma unroll
    for (int s = 0; s < 8; ++s) {
        const int off = base + s * 16;
        float4 q0 = rv ? *(const float4*)(qb + off)     : z4;
        float4 q1 = rv ? *(const float4*)(qb + off + 4) : z4;
        float4 k0 = rv ? *(const float4*)(kb + off)     : z4;
        float4 k1 = rv ? *(const float4*)(kb + off + 4) : z4;
        sq += dot4(q0, q0) + dot4(q1, q1);
        sk += dot4(k0, k0) + dot4(k1, k1);
        bf16x8 aq = pack8(q0, q1);
        bf16x8 bk = pack8(k0, k1);
        acc = __builtin_amdgcn_mfma_f32_32x32x16_bf16(aq, bk, acc, 0, 0, 0);
    }

    // sumsq: lane (row,hi) covered half the hw; pair across hi
    sq += __shfl_xor(sq, 32, 64);
    sk += __shfl_xor(sk, 32, 64);

    float* Srow = ws + ((size_t)bh * SPL + sp) * SROW;
    if (rv && hi == 0) {
        Srow[576 + row] = sq;
        Srow[600 + row] = sk;
    }
    // C/D (32x32): col j = lane&31, row i = (r&3) + 8*(r>>2) + 4*hi
    if (row < HD) {
        #pragma unroll
        for (int r = 0; r < 16; ++r) {
            int i = (r & 3) + 8 * (r >> 2) + 4 * hi;
            if (i < HD) Srow[i * HD + row] = acc[r];
        }
    }
}

// ---------------------------------------------------------------------------
// Kernel B: per (b,head): reduce Sp over 128 splits, norms, softmax, fold
// proj_w * attn * diag(kinv) into Mo[b][o][c] (bf16). grid 32, block 256.
// ---------------------------------------------------------------------------
__global__ __launch_bounds__(256) void kB(const float* __restrict__ scale,
                                          const float* __restrict__ w,
                                          float* __restrict__ ws,
                                          unsigned short* __restrict__ Mo) {
    const int bh = blockIdx.x;
    const int b  = bh >> 3;
    const int h  = bh & 7;
    const int t  = threadIdx.x;

    __shared__ float SA[624];
    __shared__ float qinv[HD], kinv[HD];
    __shared__ float wl[CH * HD];

    const float* base = ws + (size_t)bh * SPL * SROW;

    // phase 1: reduce all 624 payload floats over 128 splits (coalesced rows)
    float a0 = 0.f, a1 = 0.f, a2 = 0.f;
    const int e0 = t, e1 = t + 256, e2 = t + 512;
    for (int sp = 0; sp < SPL; ++sp) {
        const float* r = base + (size_t)sp * SROW;
        a0 += r[e0];
        a1 += r[e1];
        if (t < 112) a2 += r[e2];
    }
    SA[e0] = a0; SA[e1] = a1;
    if (t < 112) SA[e2] = a2;

    for (int idx = t; idx < CH * HD; idx += 256) {
        int o = idx / HD, dd = idx % HD;
        wl[idx] = w[o * CH + h * HD + dd];
    }
    __syncthreads();

    if (t < 2 * HD) {
        float s = SA[576 + t];
        float inv = 1.0f / fmaxf(sqrtf(s), 1e-12f);
        if (t < HD) qinv[t] = inv; else kinv[t - HD] = inv;
    }
    __syncthreads();

    const float sc = scale[h];
    for (int e = t; e < HD * HD; e += 256)
        SA[e] = SA[e] * qinv[e / HD] * kinv[e % HD] * sc;
    __syncthreads();

    if (t < HD) {   // softmax along j for row t
        float m = -1e30f;
        for (int j = 0; j < HD; ++j) m = fmaxf(m, SA[t * HD + j]);
        float sum = 0.f;
        for (int j = 0; j < HD; ++j) {
            float v = expf(SA[t * HD + j] - m);
            SA[t * HD + j] = v;
            sum += v;
        }
        float r = 1.0f / sum;
        for (int j = 0; j < HD; ++j) SA[t * HD + j] *= r;
    }
    __syncthreads();

    // Mo[b][o][h*24+j] = (sum_i w[o,h*24+i] * attn[i][j]) * kinv[j]  (bf16)
    for (int idx = t; idx < CH * HD; idx += 256) {
        int o = idx / HD, j = idx % HD;
        float v = 0.f;
        #pragma unroll
        for (int i = 0; i < HD; ++i) v = fmaf(wl[o * HD + i], SA[i * HD + j], v);
        Mo[(size_t)b * CH * CH + (size_t)o * CH + h * HD + j] = bf16rne(v * kinv[j]);
    }
}

// ---------------------------------------------------------------------------
// Kernel C: out[b][o][n] = sum_c Mo[b][o][c] * in2[b][c][n]  via mfma_32x32x16.
// Block tile: O=192 (all), N=64. 6 c-stages of 32: stage 32c x 64n fp32->bf16
// into LDS [n][c] (stride 20 u32, 16B-aligned rows), B-frags from LDS,
// A-frags straight from Mo (c-contiguous bf16). Stores: 128B-coalesced fp32.
// grid (256 nblk, 4 b), block 256.
// ---------------------------------------------------------------------------
#define KCN 64
#define BSTR 20   // u32 per n-row (16 data + 4 pad; keeps rows 16B-aligned)

__global__ __launch_bounds__(256, 4) void kC(const float* __restrict__ k,
                                             const unsigned short* __restrict__ Mo,
                                             float* __restrict__ out) {
    __shared__ unsigned int Bt[KCN * BSTR];   // 5 KB

    const int t    = threadIdx.x;
    const int lane = t & 63;
    const int wave = t >> 6;
    const int n31  = lane & 31;
    const int hi   = lane >> 5;
    const int nt   = wave & 1;          // n-tile (x32)
    const int otb  = (wave >> 1) * 3;   // first o-tile (x32) of this wave

    const int nb = blockIdx.x * KCN;
    const int b  = blockIdx.y;

    const float* kb = k + (size_t)b * CH * HW;
    const unsigned short* Mob = Mo + (size_t)b * CH * CH;

    // staging role: thread stages column n=sn, c-quarter cq (8 channels)
    const int sn = t & 63;
    const int cq = t >> 6;

    f32x16 acc[3] = {};

    for (int c0 = 0; c0 < CH; c0 += 32) {
        if (c0) __syncthreads();
        float v[8];
        #pragma unroll
        for (int cc = 0; cc < 8; ++cc)
            v[cc] = kb[(size_t)(c0 + cq * 8 + cc) * HW + nb + sn];
        unsigned int wd[4];
        #pragma unroll
        for (int g = 0; g < 4; ++g) {
            union { __hip_bfloat162 h; unsigned u; } cv;
            cv.h = __float22bfloat162_rn(float2{v[2 * g], v[2 * g + 1]});
            wd[g] = cv.u;   // low16 = c even, high16 = c odd
        }
        *(uint2*)&Bt[sn * BSTR + cq * 4]     = make_uint2(wd[0], wd[1]);
        *(uint2*)&Bt[sn * BSTR + cq * 4 + 2] = make_uint2(wd[2], wd[3]);
        __syncthreads();

        #pragma unroll
        for (int kc = 0; kc < 2; ++kc) {
            bf16x8 Bf = *(const bf16x8*)&Bt[(nt * 32 + n31) * BSTR + kc * 8 + hi * 4];
            #pragma unroll
            for (int oi = 0; oi < 3; ++oi) {
                const unsigned short* ap =
                    Mob + (size_t)((otb + oi) * 32 + n31) * CH + c0 + kc * 16 + hi * 8;
                bf16x8 Af = *(const bf16x8*)ap;
                acc[oi] = __builtin_amdgcn_mfma_f32_32x32x16_bf16(Af, Bf, acc[oi], 0, 0, 0);
            }
        }
    }

    float* op = out + (size_t)b * CH * HW;
    const int n = nb + nt * 32 + n31;
    #pragma unroll
    for (int oi = 0; oi < 3; ++oi)
        #pragma unroll
        for (int r = 0; r < 16; ++r) {
            int o = (otb + oi) * 32 + (r & 3) + 8 * (r >> 2) + 4 * hi;
            op[(size_t)o * HW + n] = acc[oi][r];
        }
}

extern "C" void kernel_launch(void* const* d_in, const int* in_sizes, int n_in,
                              void* d_out, int out_size, void* d_ws, size_t ws_size,
                              hipStream_t stream) {
    const float* in1   = (const float*)d_in[0];
    const float* in2   = (const float*)d_in[1];
    const float* scale = (const float*)d_in[2];
    const float* projw = (const float*)d_in[3];
    float* ws  = (float*)d_ws;   // needs ~10.8 MB
    float* out = (float*)d_out;
    unsigned short* Mo = (unsigned short*)(ws + OFF_MO);

    kA<<<dim3(32, SPL / 2), 128, 0, stream>>>(in1, in2, ws);
    kB<<<32, 256, 0, stream>>>(scale, projw, ws, Mo);
    kC<<<dim3(HW / KCN, BATCH), 256, 0, stream>>>(in2, Mo, out);
}

// Round 5
// 194.205 us; speedup vs baseline: 1.3455x; 1.3455x over previous
//
#include <hip/hip_runtime.h>
#include <hip/hip_bf16.h>
#include <math.h>

// Problem constants (fixed by setup_inputs)
#define BATCH 4
#define NHEAD 8
#define HD 24          // head dim
#define CH 192         // total channels
#define HW 16384       // h*w
#define SPL 64         // kA hw-chunks of 256
#define SROW 640       // Sp row: [0,576) gram, [576,600) sqq, [600,624) sqk, pad 640

// ws layout (floats):
//   Sp: [32 bh][64 sp][640]    off 0        (5.24 MB)
//   Mo: ushort[4][192][192]    off OFF_MO   (288 KB)
#define OFF_MO (32 * SPL * SROW)

#define LSTR 132   // u32 per LDS row (128 data + 4 pad; %32==4 -> 4-way max on b128)

typedef __attribute__((ext_vector_type(8)))  short bf16x8;
typedef __attribute__((ext_vector_type(16))) float f32x16;

__device__ __forceinline__ unsigned short bf16rne(float x) {
    union { float f; unsigned u; } v; v.f = x;
    unsigned u = v.u;
    return (unsigned short)((u + 0x7FFFu + ((u >> 16) & 1u)) >> 16);
}

__device__ __forceinline__ unsigned pack2(float a, float b) {
    union { __hip_bfloat162 h; unsigned u; } c;
    c.h = __float22bfloat162_rn(float2{a, b});
    return c.u;
}

// ---------------------------------------------------------------------------
// Kernel A: per (bh, 256-hw chunk): coalesced fp32 loads -> bf16 LDS tiles,
// MFMA Gram (32x32x16, 24x24 used) + QQ^T/KK^T whose diagonals supply the
// sumsq in fp32. Epilogue reduces 4 waves in (reused) LDS, writes one
// contiguous 2.5 KB Sp row. grid (32, 64), block 256.
// ---------------------------------------------------------------------------
__global__ __launch_bounds__(256, 4) void kA(const float* __restrict__ q,
                                             const float* __restrict__ k,
                                             float* __restrict__ ws) {
    __shared__ unsigned int tile[2][HD * LSTR];   // 50.7 KB total

    const int bh   = blockIdx.x;
    const int ch   = blockIdx.y;      // 0..63
    const int t    = threadIdx.x;
    const int lane = t & 63;
    const int wave = t >> 6;
    const int m    = lane & 31;
    const int hi   = lane >> 5;

    const float* qb = q + (size_t)bh * HD * HW + ch * 256;
    const float* kb = k + (size_t)bh * HD * HW + ch * 256;

    // ---- stage: 24 rows x 256 hw, fp32 -> bf16, 1KB/instr coalesced ----
    #pragma unroll
    for (int j = 0; j < 6; ++j) {
        const int idx = j * 256 + t;        // 0..1535
        const int row = idx >> 6;           // 0..23
        const int c64 = idx & 63;
        float4 qv = *(const float4*)(qb + (size_t)row * HW + c64 * 4);
        float4 kv = *(const float4*)(kb + (size_t)row * HW + c64 * 4);
        *(uint2*)&tile[0][row * LSTR + c64 * 2] = make_uint2(pack2(qv.x, qv.y), pack2(qv.z, qv.w));
        *(uint2*)&tile[1][row * LSTR + c64 * 2] = make_uint2(pack2(kv.x, kv.y), pack2(kv.z, kv.w));
    }
    __syncthreads();

    // ---- MFMA: per wave 4 k-steps of 16 hw ----
    const int rowc = (m < HD) ? m : 0;     // clamp: garbage only hits discarded C
    f32x16 aQK = {}, aQQ = {}, aKK = {};
    #pragma unroll
    for (int s = 0; s < 4; ++s) {
        const int off = (wave * 64 + s * 16) >> 1;    // u32 offset within row
        bf16x8 aq = *(const bf16x8*)&tile[0][rowc * LSTR + off + hi * 4];
        bf16x8 bk = *(const bf16x8*)&tile[1][rowc * LSTR + off + hi * 4];
        aQK = __builtin_amdgcn_mfma_f32_32x32x16_bf16(aq, bk, aQK, 0, 0, 0);
        aQQ = __builtin_amdgcn_mfma_f32_32x32x16_bf16(aq, aq, aQQ, 0, 0, 0);
        aKK = __builtin_amdgcn_mfma_f32_32x32x16_bf16(bk, bk, aKK, 0, 0, 0);
    }
    __syncthreads();           // all frag reads done -> safe to reuse tile

    // ---- scatter partials: red[wave][624] over the tile memory ----
    float* red = (float*)tile;
    // C/D (32x32): col j = lane&31, row i = (r&3) + 8*(r>>2) + 4*hi
    if (m < HD) {
        #pragma unroll
        for (int r = 0; r < 16; ++r) {
            const int i = (r & 3) + 8 * (r >> 2) + 4 * hi;
            if (i < HD) {
                red[wave * 624 + i * HD + m] = aQK[r];
                if (i == m) {                      // diagonals = sumsq
                    red[wave * 624 + 576 + i] = aQQ[r];
                    red[wave * 624 + 600 + i] = aKK[r];
                }
            }
        }
    }
    __syncthreads();

    float* Srow = ws + ((size_t)bh * SPL + ch) * SROW;
    for (int e = t; e < 624; e += 256)
        Srow[e] = red[e] + red[624 + e] + red[1248 + e] + red[1872 + e];
}

// ---------------------------------------------------------------------------
// Kernel B: per (b,head): reduce Sp over 64 chunks, norms, softmax, fold
// proj_w * attn * diag(kinv) into Mo[b][o][c] (bf16). grid 32, block 256.
// ---------------------------------------------------------------------------
__global__ __launch_bounds__(256) void kB(const float* __restrict__ scale,
                                          const float* __restrict__ w,
                                          float* __restrict__ ws,
                                          unsigned short* __restrict__ Mo) {
    const int bh = blockIdx.x;
    const int b  = bh >> 3;
    const int h  = bh & 7;
    const int t  = threadIdx.x;

    __shared__ float SA[624];
    __shared__ float qinv[HD], kinv[HD];
    __shared__ float wl[CH * HD];

    const float* base = ws + (size_t)bh * SPL * SROW;

    float a0 = 0.f, a1 = 0.f, a2 = 0.f;
    const int e0 = t, e1 = t + 256, e2 = t + 512;
    for (int sp = 0; sp < SPL; ++sp) {
        const float* r = base + (size_t)sp * SROW;
        a0 += r[e0];
        a1 += r[e1];
        if (t < 112) a2 += r[e2];
    }
    SA[e0] = a0; SA[e1] = a1;
    if (t < 112) SA[e2] = a2;

    for (int idx = t; idx < CH * HD; idx += 256) {
        int o = idx / HD, dd = idx % HD;
        wl[idx] = w[o * CH + h * HD + dd];
    }
    __syncthreads();

    if (t < 2 * HD) {
        float s = SA[576 + t];
        float inv = 1.0f / fmaxf(sqrtf(s), 1e-12f);
        if (t < HD) qinv[t] = inv; else kinv[t - HD] = inv;
    }
    __syncthreads();

    const float sc = scale[h];
    for (int e = t; e < HD * HD; e += 256)
        SA[e] = SA[e] * qinv[e / HD] * kinv[e % HD] * sc;
    __syncthreads();

    if (t < HD) {   // softmax along j for row t
        float m = -1e30f;
        for (int j = 0; j < HD; ++j) m = fmaxf(m, SA[t * HD + j]);
        float sum = 0.f;
        for (int j = 0; j < HD; ++j) {
            float v = expf(SA[t * HD + j] - m);
            SA[t * HD + j] = v;
            sum += v;
        }
        float r = 1.0f / sum;
        for (int j = 0; j < HD; ++j) SA[t * HD + j] *= r;
    }
    __syncthreads();

    // Mo[b][o][h*24+j] = (sum_i w[o,h*24+i] * attn[i][j]) * kinv[j]  (bf16)
    for (int idx = t; idx < CH * HD; idx += 256) {
        int o = idx / HD, j = idx % HD;
        float v = 0.f;
        #pragma unroll
        for (int i = 0; i < HD; ++i) v = fmaf(wl[o * HD + i], SA[i * HD + j], v);
        Mo[(size_t)b * CH * CH + (size_t)o * CH + h * HD + j] = bf16rne(v * kinv[j]);
    }
}

// ---------------------------------------------------------------------------
// Kernel C: out[b][o][n] = sum_c Mo[b][o][c] * in2[b][c][n]  via mfma_32x32x16.
// Block tile: O=192 (all), N=64. 6 c-stages of 32: stage 32c x 64n fp32->bf16
// into LDS [n][c] (stride 20 u32), B-frags from LDS, A-frags from Mo.
// grid (256 nblk, 4 b), block 256.
// ---------------------------------------------------------------------------
#define KCN 64
#define BSTR 20   // u32 per n-row (16 data + 4 pad)

__global__ __launch_bounds__(256, 4) void kC(const float* __restrict__ k,
                                             const unsigned short* __restrict__ Mo,
                                             float* __restrict__ out) {
    __shared__ unsigned int Bt[KCN * BSTR];   // 5 KB

    const int t    = threadIdx.x;
    const int lane = t & 63;
    const int wave = t >> 6;
    const int n31  = lane & 31;
    const int hi   = lane >> 5;
    const int nt   = wave & 1;          // n-tile (x32)
    const int otb  = (wave >> 1) * 3;   // first o-tile (x32) of this wave

    const int nb = blockIdx.x * KCN;
    const int b  = blockIdx.y;

    const float* kb = k + (size_t)b * CH * HW;
    const unsigned short* Mob = Mo + (size_t)b * CH * CH;

    const int sn = t & 63;
    const int cq = t >> 6;

    f32x16 acc[3] = {};

    for (int c0 = 0; c0 < CH; c0 += 32) {
        if (c0) __syncthreads();
        float v[8];
        #pragma unroll
        for (int cc = 0; cc < 8; ++cc)
            v[cc] = kb[(size_t)(c0 + cq * 8 + cc) * HW + nb + sn];
        unsigned int wd[4];
        #pragma unroll
        for (int g = 0; g < 4; ++g) wd[g] = pack2(v[2 * g], v[2 * g + 1]);
        *(uint2*)&Bt[sn * BSTR + cq * 4]     = make_uint2(wd[0], wd[1]);
        *(uint2*)&Bt[sn * BSTR + cq * 4 + 2] = make_uint2(wd[2], wd[3]);
        __syncthreads();

        #pragma unroll
        for (int kc = 0; kc < 2; ++kc) {
            bf16x8 Bf = *(const bf16x8*)&Bt[(nt * 32 + n31) * BSTR + kc * 8 + hi * 4];
            #pragma unroll
            for (int oi = 0; oi < 3; ++oi) {
                const unsigned short* ap =
                    Mob + (size_t)((otb + oi) * 32 + n31) * CH + c0 + kc * 16 + hi * 8;
                bf16x8 Af = *(const bf16x8*)ap;
                acc[oi] = __builtin_amdgcn_mfma_f32_32x32x16_bf16(Af, Bf, acc[oi], 0, 0, 0);
            }
        }
    }

    float* op = out + (size_t)b * CH * HW;
    const int n = nb + nt * 32 + n31;
    #pragma unroll
    for (int oi = 0; oi < 3; ++oi)
        #pragma unroll
        for (int r = 0; r < 16; ++r) {
            int o = (otb + oi) * 32 + (r & 3) + 8 * (r >> 2) + 4 * hi;
            op[(size_t)o * HW + n] = acc[oi][r];
        }
}

extern "C" void kernel_launch(void* const* d_in, const int* in_sizes, int n_in,
                              void* d_out, int out_size, void* d_ws, size_t ws_size,
                              hipStream_t stream) {
    const float* in1   = (const float*)d_in[0];
    const float* in2   = (const float*)d_in[1];
    const float* scale = (const float*)d_in[2];
    const float* projw = (const float*)d_in[3];
    float* ws  = (float*)d_ws;   // needs ~5.6 MB
    float* out = (float*)d_out;
    unsigned short* Mo = (unsigned short*)(ws + OFF_MO);

    kA<<<dim3(32, SPL), 256, 0, stream>>>(in1, in2, ws);
    kB<<<32, 256, 0, stream>>>(scale, projw, ws, Mo);
    kC<<<dim3(HW / KCN, BATCH), 256, 0, stream>>>(in2, Mo, out);
}

// Round 6
// 176.056 us; speedup vs baseline: 1.4842x; 1.1031x over previous
//
#include <hip/hip_runtime.h>
#include <hip/hip_bf16.h>
#include <math.h>

// Problem constants (fixed by setup_inputs)
#define BATCH 4
#define NHEAD 8
#define HD 24          // head dim
#define CH 192         // total channels
#define HW 16384       // h*w
#define SPL 64         // kA hw-chunks of 256
#define SROW 640       // Sp row: [0,576) gram, [576,600) sqq, [600,624) sqk, pad 640

// ws layout (floats):
//   Sp: [32 bh][64 sp][640]    off 0        (5.24 MB)
//   Mo: ushort[4][192][192]    off OFF_MO   (288 KB)
#define OFF_MO (32 * SPL * SROW)

#define LSTR 132   // u32 per kA LDS row (128 data + 4 pad)

typedef __attribute__((ext_vector_type(8)))  short bf16x8;
typedef __attribute__((ext_vector_type(16))) float f32x16;

__device__ __forceinline__ unsigned short bf16rne(float x) {
    union { float f; unsigned u; } v; v.f = x;
    unsigned u = v.u;
    return (unsigned short)((u + 0x7FFFu + ((u >> 16) & 1u)) >> 16);
}

__device__ __forceinline__ unsigned pack2(float a, float b) {
    union { __hip_bfloat162 h; unsigned u; } c;
    c.h = __float22bfloat162_rn(float2{a, b});
    return c.u;
}

// ---------------------------------------------------------------------------
// Kernel A (unchanged from R5): per (bh, 256-hw chunk): coalesced fp32 loads
// -> bf16 LDS tiles, MFMA Gram (32x32x16) + QQ^T/KK^T diagonals = sumsq.
// grid (32, 64), block 256.
// ---------------------------------------------------------------------------
__global__ __launch_bounds__(256, 4) void kA(const float* __restrict__ q,
                                             const float* __restrict__ k,
                                             float* __restrict__ ws) {
    __shared__ unsigned int tile[2][HD * LSTR];   // 25.3 KB total

    const int bh   = blockIdx.x;
    const int ch   = blockIdx.y;      // 0..63
    const int t    = threadIdx.x;
    const int lane = t & 63;
    const int wave = t >> 6;
    const int m    = lane & 31;
    const int hi   = lane >> 5;

    const float* qb = q + (size_t)bh * HD * HW + ch * 256;
    const float* kb = k + (size_t)bh * HD * HW + ch * 256;

    #pragma unroll
    for (int j = 0; j < 6; ++j) {
        const int idx = j * 256 + t;        // 0..1535
        const int row = idx >> 6;           // 0..23
        const int c64 = idx & 63;
        float4 qv = *(const float4*)(qb + (size_t)row * HW + c64 * 4);
        float4 kv = *(const float4*)(kb + (size_t)row * HW + c64 * 4);
        *(uint2*)&tile[0][row * LSTR + c64 * 2] = make_uint2(pack2(qv.x, qv.y), pack2(qv.z, qv.w));
        *(uint2*)&tile[1][row * LSTR + c64 * 2] = make_uint2(pack2(kv.x, kv.y), pack2(kv.z, kv.w));
    }
    __syncthreads();

    const int rowc = (m < HD) ? m : 0;     // clamp: garbage only hits discarded C
    f32x16 aQK = {}, aQQ = {}, aKK = {};
    #pragma unroll
    for (int s = 0; s < 4; ++s) {
        const int off = (wave * 64 + s * 16) >> 1;
        bf16x8 aq = *(const bf16x8*)&tile[0][rowc * LSTR + off + hi * 4];
        bf16x8 bk = *(const bf16x8*)&tile[1][rowc * LSTR + off + hi * 4];
        aQK = __builtin_amdgcn_mfma_f32_32x32x16_bf16(aq, bk, aQK, 0, 0, 0);
        aQQ = __builtin_amdgcn_mfma_f32_32x32x16_bf16(aq, aq, aQQ, 0, 0, 0);
        aKK = __builtin_amdgcn_mfma_f32_32x32x16_bf16(bk, bk, aKK, 0, 0, 0);
    }
    __syncthreads();

    float* red = (float*)tile;
    if (m < HD) {
        #pragma unroll
        for (int r = 0; r < 16; ++r) {
            const int i = (r & 3) + 8 * (r >> 2) + 4 * hi;
            if (i < HD) {
                red[wave * 624 + i * HD + m] = aQK[r];
                if (i == m) {
                    red[wave * 624 + 576 + i] = aQQ[r];
                    red[wave * 624 + 600 + i] = aKK[r];
                }
            }
        }
    }
    __syncthreads();

    float* Srow = ws + ((size_t)bh * SPL + ch) * SROW;
    for (int e = t; e < 624; e += 256)
        Srow[e] = red[e] + red[624 + e] + red[1248 + e] + red[1872 + e];
}

// ---------------------------------------------------------------------------
// Kernel B: per (b,head). 1024 threads: 4 groups reduce 16 splits each in
// parallel, LDS combine, norms, softmax, fold into Mo (bf16). grid 32.
// ---------------------------------------------------------------------------
__global__ __launch_bounds__(1024) void kB(const float* __restrict__ scale,
                                           const float* __restrict__ w,
                                           float* __restrict__ ws,
                                           unsigned short* __restrict__ Mo) {
    const int bh = blockIdx.x;
    const int b  = bh >> 3;
    const int h  = bh & 7;
    const int t  = threadIdx.x;   // 0..1023
    const int g  = t >> 8;        // split-group 0..3
    const int u  = t & 255;

    __shared__ float part[4][624];
    __shared__ float SA[624];
    __shared__ float qinv[HD], kinv[HD];
    __shared__ float wl[CH * HD];

    const float* base = ws + (size_t)bh * SPL * SROW;

    float a0 = 0.f, a1 = 0.f, a2 = 0.f;
    for (int sp = g * 16; sp < g * 16 + 16; ++sp) {
        const float* r = base + (size_t)sp * SROW;
        a0 += r[u];
        a1 += r[u + 256];
        if (u < 112) a2 += r[u + 512];
    }
    part[g][u] = a0;
    part[g][u + 256] = a1;
    if (u < 112) part[g][u + 512] = a2;

    for (int idx = t; idx < CH * HD; idx += 1024) {
        int o = idx / HD, dd = idx % HD;
        wl[idx] = w[o * CH + h * HD + dd];
    }
    __syncthreads();

    if (t < 624) SA[t] = part[0][t] + part[1][t] + part[2][t] + part[3][t];
    __syncthreads();

    if (t < 2 * HD) {
        float inv = 1.0f / fmaxf(sqrtf(SA[576 + t]), 1e-12f);
        if (t < HD) qinv[t] = inv; else kinv[t - HD] = inv;
    }
    __syncthreads();

    const float sc = scale[h];
    if (t < 576) SA[t] = SA[t] * qinv[t / HD] * kinv[t % HD] * sc;
    __syncthreads();

    if (t < HD) {   // softmax along j for row t
        float m = -1e30f;
        for (int j = 0; j < HD; ++j) m = fmaxf(m, SA[t * HD + j]);
        float sum = 0.f;
        for (int j = 0; j < HD; ++j) {
            float v = expf(SA[t * HD + j] - m);
            SA[t * HD + j] = v;
            sum += v;
        }
        float r = 1.0f / sum;
        for (int j = 0; j < HD; ++j) SA[t * HD + j] *= r;
    }
    __syncthreads();

    // Mo[b][o][h*24+j] = (sum_i w[o,h*24+i] * attn[i][j]) * kinv[j]  (bf16)
    for (int idx = t; idx < CH * HD; idx += 1024) {
        int o = idx / HD, j = idx % HD;
        float v = 0.f;
        #pragma unroll
        for (int i = 0; i < HD; ++i) v = fmaf(wl[o * HD + i], SA[i * HD + j], v);
        Mo[(size_t)b * CH * CH + (size_t)o * CH + h * HD + j] = bf16rne(v * kinv[j]);
    }
}

// ---------------------------------------------------------------------------
// Kernel C: out[b][o][n] = sum_c Mo[b][o][c] * in2[b][c][n]  via mfma_32x32x16.
// Block tile O=192 x N=64. 3 c-stages of 64: float2 global loads (512B/instr),
// fp32->bf16 into LDS [n][c] (stride 36 u32), 12 MFMAs/stage. Half the
// barriers of the 32-c version. grid (256 nblk, 4 b), block 256.
// ---------------------------------------------------------------------------
#define KCN 64
#define CSTEP 64
#define BSTR2 36   // u32 per n-row (32 data + 4 pad; multiple of 4 for b128)

__global__ __launch_bounds__(256, 4) void kC(const float* __restrict__ k,
                                             const unsigned short* __restrict__ Mo,
                                             float* __restrict__ out) {
    __shared__ unsigned int Bt[KCN * BSTR2];   // 9.2 KB

    const int t    = threadIdx.x;
    const int lane = t & 63;
    const int wave = t >> 6;
    const int n31  = lane & 31;
    const int hi   = lane >> 5;
    const int nt   = wave & 1;          // n-tile (x32)
    const int otb  = (wave >> 1) * 3;   // first o-tile (x32) of this wave

    const int nb = blockIdx.x * KCN;
    const int b  = blockIdx.y;

    const float* kb = k + (size_t)b * CH * HW;
    const unsigned short* Mob = Mo + (size_t)b * CH * CH;

    const int np = t & 31;   // n-pair: stages n = np*2, np*2+1
    const int cg = t >> 5;   // 0..7: channels cg*8 .. cg*8+7

    f32x16 acc[3] = {};

    for (int c0 = 0; c0 < CH; c0 += CSTEP) {   // 3 stages
        if (c0) __syncthreads();
        float2 v[8];
        #pragma unroll
        for (int cc = 0; cc < 8; ++cc)
            v[cc] = *(const float2*)(kb + (size_t)(c0 + cg * 8 + cc) * HW + nb + np * 2);
        unsigned int w0[4], w1[4];
        #pragma unroll
        for (int g = 0; g < 4; ++g) {
            w0[g] = pack2(v[2 * g].x, v[2 * g + 1].x);   // row n0:   channels (2g, 2g+1)
            w1[g] = pack2(v[2 * g].y, v[2 * g + 1].y);   // row n0+1
        }
        const int n0 = np * 2;
        *(uint2*)&Bt[n0 * BSTR2 + cg * 4]           = make_uint2(w0[0], w0[1]);
        *(uint2*)&Bt[n0 * BSTR2 + cg * 4 + 2]       = make_uint2(w0[2], w0[3]);
        *(uint2*)&Bt[(n0 + 1) * BSTR2 + cg * 4]     = make_uint2(w1[0], w1[1]);
        *(uint2*)&Bt[(n0 + 1) * BSTR2 + cg * 4 + 2] = make_uint2(w1[2], w1[3]);
        __syncthreads();

        #pragma unroll
        for (int kc = 0; kc < 4; ++kc) {
            bf16x8 Bf = *(const bf16x8*)&Bt[(nt * 32 + n31) * BSTR2 + kc * 8 + hi * 4];
            #pragma unroll
            for (int oi = 0; oi < 3; ++oi) {
                const unsigned short* ap =
                    Mob + (size_t)((otb + oi) * 32 + n31) * CH + c0 + kc * 16 + hi * 8;
                bf16x8 Af = *(const bf16x8*)ap;
                acc[oi] = __builtin_amdgcn_mfma_f32_32x32x16_bf16(Af, Bf, acc[oi], 0, 0, 0);
            }
        }
    }

    float* op = out + (size_t)b * CH * HW;
    const int n = nb + nt * 32 + n31;
    #pragma unroll
    for (int oi = 0; oi < 3; ++oi)
        #pragma unroll
        for (int r = 0; r < 16; ++r) {
            int o = (otb + oi) * 32 + (r & 3) + 8 * (r >> 2) + 4 * hi;
            op[(size_t)o * HW + n] = acc[oi][r];
        }
}

extern "C" void kernel_launch(void* const* d_in, const int* in_sizes, int n_in,
                              void* d_out, int out_size, void* d_ws, size_t ws_size,
                              hipStream_t stream) {
    const float* in1   = (const float*)d_in[0];
    const float* in2   = (const float*)d_in[1];
    const float* scale = (const float*)d_in[2];
    const float* projw = (const float*)d_in[3];
    float* ws  = (float*)d_ws;   // needs ~5.6 MB
    float* out = (float*)d_out;
    unsigned short* Mo = (unsigned short*)(ws + OFF_MO);

    kA<<<dim3(32, SPL), 256, 0, stream>>>(in1, in2, ws);
    kB<<<32, 1024, 0, stream>>>(scale, projw, ws, Mo);
    kC<<<dim3(HW / KCN, BATCH), 256, 0, stream>>>(in2, Mo, out);
}